// Round 7
// baseline (1342.207 us; speedup 1.0000x reference)
//
#include <hip/hip_runtime.h>
#include <cfloat>
#include <cstdint>
#include <cstddef>

// Problem constants
#define M_ROWS 16384
#define NE     8192
#define KD     256

// d_out layout (float elements)
#define OFF_LOSS   0ULL
#define OFF_ZQ     1ULL
#define OFF_PERP   4194305ULL
#define OFF_ONEHOT 4194306ULL
#define OFF_I0     138412034ULL
#define OFF_I1     138428418ULL

// Scratch inside the one-hot output region (zeroed AFTER use).
// base = out + OFF_ONEHOT + 2 (16B-aligned). Offsets in floats:
#define SCR_Z16  0ULL         // fp16[16384][256] swizzled K-blocked
#define SCR_E16  2097152ULL   // fp16[8192][256] swizzled (x256 scale)
#define SCR_PART 3145728ULL   // float4[16384][8][2]
#define SCR_Z32T 4194304ULL   // fp32[16384][256] row-major transposed z

// d_ws layout (4-byte units)
#define WS_I0    0        // int[16384]
#define WS_HIST  16384    // int[8192]
#define WS_ENORM 24576    // float[8192]
#define WS_CNORM 32768    // float[16384]
#define WS_T0SUM 49152    // double (2 slots, 8B-aligned)
#define WS_TOTAL 49154

typedef _Float16 fp16x8 __attribute__((ext_vector_type(8)));
typedef float    floatx16 __attribute__((ext_vector_type(16)));

__device__ __forceinline__ void async_load16(const void* g, void* lds) {
    __builtin_amdgcn_global_load_lds(
        (const __attribute__((address_space(1))) void*)g,
        (__attribute__((address_space(3))) void*)lds, 16, 0, 0);
}

// ---------------------------------------------------------------- zero ws
__global__ void zero_ws_kernel(float* __restrict__ ws) {
    int i = blockIdx.x * 256 + threadIdx.x;
    if (i < WS_TOTAL) ws[i] = 0.0f;
}

// ------------------------------------------------- zero one-hot region (537 MB)
__global__ void zero_onehot_kernel(float* __restrict__ out) {
    size_t tidg = (size_t)blockIdx.x * 1024 + threadIdx.x;   // 4096 x 1024
    float4* base = (float4*)(out + OFF_ONEHOT + 2);
    const float4 zz = make_float4(0.f, 0.f, 0.f, 0.f);
#pragma unroll
    for (int i = 0; i < 8; i++) {
        size_t q = tidg + (size_t)i * 4194304ULL;
        if (q < 33554431ULL) base[q] = zz;
    }
    if (tidg == 0) {
        out[OFF_ONEHOT + 0] = 0.f;
        out[OFF_ONEHOT + 1] = 0.f;
        out[OFF_ONEHOT + 134217726ULL] = 0.f;
        out[OFF_ONEHOT + 134217727ULL] = 0.f;
    }
}

// ---------------------------------------------------------------- scatter ones
__global__ void scatter_ones_kernel(const int* __restrict__ ws_i0, float* __restrict__ out) {
    int r = blockIdx.x * 256 + threadIdx.x;   // 64 x 256
    int j = ws_i0[r] & (NE - 1);
    out[OFF_ONEHOT + (size_t)r * NE + j] = 1.0f;
}

// ------------------------------------------------------------------------
// numpy float32 pairwise sum over 256 elements, emulated exactly (validated R2)
__device__ __forceinline__ float pairwise16(const float* sq, int lane16) {
    const int h = lane16 >> 3;
    const int j = lane16 & 7;
    float r = sq[h * 128 + j];
#pragma unroll
    for (int i = 1; i < 16; i++) r = r + sq[h * 128 + i * 8 + j];
    float s = r + __shfl_xor(r, 1);
    s = s + __shfl_xor(s, 2);
    s = s + __shfl_xor(s, 4);
    s = s + __shfl_xor(s, 8);
    return s;
}

// ---------------------------------------------------------------- E_j emulation
__global__ void enorm_kernel(const float* __restrict__ emb, float* __restrict__ enorm) {
    __shared__ float sq[16][257];
    const int tid = threadIdx.x;
    const int row0 = blockIdx.x * 16;
#pragma unroll
    for (int p = 0; p < 4; p++) {
        int q = p * 256 + tid;
        int rl = q >> 6, kq = q & 63;
        float4 v = *(const float4*)(emb + (size_t)(row0 + rl) * KD + kq * 4);
        sq[rl][kq * 4 + 0] = v.x * v.x;
        sq[rl][kq * 4 + 1] = v.y * v.y;
        sq[rl][kq * 4 + 2] = v.z * v.z;
        sq[rl][kq * 4 + 3] = v.w * v.w;
    }
    __syncthreads();
    const int rl = tid >> 4, lane16 = tid & 15;
    float s = pairwise16(&sq[rl][0], lane16);
    if (lane16 == 0) enorm[row0 + rl] = s;
}

// ---------------------------------------------------------------- C_r emulation
__global__ void cnorm_kernel(const float* __restrict__ z, float* __restrict__ cnorm) {
    __shared__ float sq[16][257];
    const int tid = threadIdx.x;
    const int r0  = blockIdx.x * 16;
    const int b   = r0 >> 10;
    const int hw0 = r0 & 1023;
    const float* zb = z + ((size_t)b << 18) + hw0;
#pragma unroll
    for (int p = 0; p < 4; p++) {
        int q = p * 256 + tid;
        int c = q >> 2, hq = q & 3;
        float4 v = *(const float4*)(zb + ((size_t)c << 10) + hq * 4);
        sq[hq * 4 + 0][c] = v.x * v.x;
        sq[hq * 4 + 1][c] = v.y * v.y;
        sq[hq * 4 + 2][c] = v.z * v.z;
        sq[hq * 4 + 3][c] = v.w * v.w;
    }
    __syncthreads();
    const int rl = tid >> 4, lane16 = tid & 15;
    float s = pairwise16(&sq[rl][0], lane16);
    if (lane16 == 0) cnorm[r0 + rl] = s;
}

// ---------------------------------------------------------------- z -> fp16 swizzled + fp32 transposed
// fp16 layout: unit = ((r>>7)*4 + kb)*1024 + (r&127)*8 + (k8 ^ (r&7)); 128x64 tile contiguous.
__global__ void split_z_kernel(const float* __restrict__ z, _Float16* __restrict__ z16,
                               float* __restrict__ z32t) {
    __shared__ float tile[64][65];
    const int tid = threadIdx.x;            // 256
    const int r0  = blockIdx.x * 64;        // 256 row-blocks
    const int kb  = blockIdx.y;             // 4 k-blocks of 64
    const int b   = r0 >> 10;
    const int hw0 = r0 & 1023;
#pragma unroll
    for (int p = 0; p < 4; p++) {
        int q = p * 256 + tid;
        int cl = q >> 4, hq = q & 15;
        float4 v = *(const float4*)(z + ((size_t)b << 18) + (size_t)(kb * 64 + cl) * 1024 + hw0 + hq * 4);
        tile[hq * 4 + 0][cl] = v.x;
        tile[hq * 4 + 1][cl] = v.y;
        tile[hq * 4 + 2][cl] = v.z;
        tile[hq * 4 + 3][cl] = v.w;
    }
    __syncthreads();
#pragma unroll
    for (int p = 0; p < 2; p++) {
        int u = p * 256 + tid;              // 512 octets: 64 rows x 8 k8
        int row = u >> 3, k8 = u & 7;
        int r = r0 + row;
        fp16x8 vh;
#pragma unroll
        for (int e = 0; e < 8; e++) vh[e] = (_Float16)tile[row][k8 * 8 + e];
        size_t unit = ((size_t)(r >> 7) * 4 + kb) * 1024 + (size_t)(r & 127) * 8 + (k8 ^ (r & 7));
        *(fp16x8*)(z16 + unit * 8) = vh;
    }
    // fp32 transposed row-major copy for rescore (coalesced)
#pragma unroll
    for (int p = 0; p < 4; p++) {
        int q = p * 256 + tid;              // 1024 quads: 64 rows x 16
        int row = q >> 4, co = (q & 15) * 4;
        float4 v = make_float4(tile[row][co], tile[row][co + 1], tile[row][co + 2], tile[row][co + 3]);
        *(float4*)(z32t + (size_t)(r0 + row) * 256 + kb * 64 + co) = v;
    }
}

// ---------------------------------------------------------------- e -> fp16*256 (same layout)
__global__ void split_e_kernel(const float* __restrict__ emb, _Float16* __restrict__ e16) {
    int u = blockIdx.x * 256 + threadIdx.x;   // 1024 x 256 = 262144 octets
    size_t go = (size_t)u * 8;                // = code*256 + kc*64 + ku8*8
    float4 v0 = *(const float4*)(emb + go);
    float4 v1 = *(const float4*)(emb + go + 4);
    float x[8] = {v0.x, v0.y, v0.z, v0.w, v1.x, v1.y, v1.z, v1.w};
    fp16x8 vh;
#pragma unroll
    for (int e = 0; e < 8; e++) vh[e] = (_Float16)(x[e] * 256.0f);
    int code = u >> 5, kc = (u >> 3) & 3, ku8 = u & 7;
    int kj = ku8 ^ (code & 7);
    size_t unit = ((size_t)(code >> 7) * 4 + kc) * 1024 + (size_t)(code & 127) * 8 + kj;
    *(fp16x8*)(e16 + unit * 8) = vh;
}

// ---------------------------------------------------------------- helpers
__device__ __forceinline__ fp16x8 frag_ld(const _Float16* lds, int rc, int ku) {
    int slot = rc * 8 + (ku ^ (rc & 7));
    return *(const fp16x8*)(lds + slot * 8);
}

#define MFMA(d, a, b) d = __builtin_amdgcn_mfma_f32_32x32x16_f16(a, b, d, 0, 0, 0)

__device__ __forceinline__ bool lex_lt(float t, int i, float T, int I) {
    return (t < T) || (t == T && i < I);
}

__device__ __forceinline__ void ins4(float t, int i,
    float& t0, int& i0, float& t1, int& i1,
    float& t2, int& i2, float& t3, int& i3) {
    if (lex_lt(t, i, t3, i3)) {
        if (lex_lt(t, i, t2, i2)) {
            t3 = t2; i3 = i2;
            if (lex_lt(t, i, t1, i1)) {
                t2 = t1; i2 = i1;
                if (lex_lt(t, i, t0, i0)) { t1 = t0; i1 = i0; t0 = t; i0 = i; }
                else { t1 = t; i1 = i; }
            } else { t2 = t; i2 = i; }
        } else { t3 = t; i3 = i; }
    }
}

// ---------------------------------------------------------------- MFMA top-4 filter (fp16)
// Block: 512 thr (8 waves: wave_m = wid&1 over codes, wave_n = wid>>1 over 4x32 zrows).
// z panel (128 rows x 256 k) persistent in LDS; e tiles (128 codes x 64 k) double-buffered.
// Grid (jg=8 fastest, zb=128): same-jg blocks land on one XCD (round-robin) -> e stays in its L2.
__launch_bounds__(512, 1)
__global__ void mfma_top4_kernel(const _Float16* __restrict__ e16, const _Float16* __restrict__ z16,
                                 const float* __restrict__ enorm_g, const float* __restrict__ cnorm_g,
                                 float4* __restrict__ part) {
    __shared__ _Float16 Zs[32768];     // 64 KB: 4 kc-sections of 1024 units
    __shared__ _Float16 Es[2][8192];   // 2 x 16 KB
    __shared__ float en_all[1024];     // 4 KB
    __shared__ float mbuf[128][8];     // 4 KB

    const int tid = threadIdx.x;
    const int lane = tid & 63, wid = tid >> 6;
    const int l31 = lane & 31, half = lane >> 5;
    const int wave_m = wid & 1, wave_n = wid >> 1;   // wave_n 0..3
    const int jg = blockIdx.x, zb = blockIdx.y;
    const int brow0 = zb * 128;

    const int rcA0 = wave_m * 64 + l31, rcA1 = rcA0 + 32;
    const int rcB  = wave_n * 32 + l31;

    // e-norms for this jg
#pragma unroll
    for (int p = 0; p < 2; p++) en_all[p * 512 + tid] = enorm_g[jg * 1024 + p * 512 + tid];

    const float Cn = cnorm_g[brow0 + rcB];

    // prologue: stage persistent z panel (4096 units, contiguous 64 KB) + first e tile
#pragma unroll
    for (int p = 0; p < 8; p++) {
        int ub = p * 512 + wid * 64;
        async_load16((const void*)(z16 + ((size_t)zb * 4096 + ub + lane) * 8),
                     (void*)(Zs + (size_t)ub * 8));
    }
#pragma unroll
    for (int p = 0; p < 2; p++) {
        int ub = p * 512 + wid * 64;
        async_load16((const void*)(e16 + ((size_t)(jg * 8 + 0) * 4096 + ub + lane) * 8),
                     (void*)(Es[0] + (size_t)ub * 8));
    }
    __syncthreads();

    float q0 = FLT_MAX, q1 = FLT_MAX, q2 = FLT_MAX, q3 = FLT_MAX;
    int   j0 = 0x7fffffff, j1 = 0x7fffffff, j2 = 0x7fffffff, j3 = 0x7fffffff;

    floatx16 acc0, acc1;
    for (int iter = 0; iter < 32; iter++) {
        const int jt = iter >> 2, kc = iter & 3;
        const int cur = iter & 1;
        if (kc == 0) { acc0 = (floatx16)0.f; acc1 = (floatx16)0.f; }
        if (iter < 31) {
            const int ni = iter + 1, njt = ni >> 2, nkc = ni & 3;
#pragma unroll
            for (int p = 0; p < 2; p++) {
                int ub = p * 512 + wid * 64;
                async_load16((const void*)(e16 + ((size_t)((jg * 8 + njt) * 4 + nkc) * 1024 + ub + lane) * 8),
                             (void*)(Es[cur ^ 1] + (size_t)ub * 8));
            }
        }
        const _Float16* zsec = Zs + kc * 8192;
#pragma unroll
        for (int ks = 0; ks < 4; ks++) {
            const int ku = ks * 2 + half;
            fp16x8 a0 = frag_ld(Es[cur], rcA0, ku);
            fp16x8 a1 = frag_ld(Es[cur], rcA1, ku);
            fp16x8 b0 = frag_ld(zsec, rcB, ku);
            MFMA(acc0, a0, b0);
            MFMA(acc1, a1, b0);
        }
        if (kc == 3) {
            const int jbase = jg * 1024 + jt * 128;
            // C/D 32x32: col = lane&31 (zrow), row = (reg&3)+8*(reg>>2)+4*half (code)
#pragma unroll
            for (int a = 0; a < 2; a++) {
#pragma unroll
                for (int reg = 0; reg < 16; reg++) {
                    const int rl = (reg & 3) + 8 * (reg >> 2) + 4 * half;
                    const int cl = wave_m * 64 + a * 32 + rl;
                    const int code = jbase + cl;
                    const float E = en_all[jt * 128 + cl];
                    float g = (a == 0) ? acc0[reg] : acc1[reg];
                    float t = fmaf(-0.0078125f, g, Cn + E);   // -2/256 * acc
                    ins4(t, code, q0, j0, q1, j1, q2, j2, q3, j3);
                }
            }
        }
        __syncthreads();
    }

    // lane <-> lane+32 merge (same zrow, complementary code sets)
    {
        float ot0 = __shfl_xor(q0, 32), ot1 = __shfl_xor(q1, 32),
              ot2 = __shfl_xor(q2, 32), ot3 = __shfl_xor(q3, 32);
        int oi0 = __shfl_xor(j0, 32), oi1 = __shfl_xor(j1, 32),
            oi2 = __shfl_xor(j2, 32), oi3 = __shfl_xor(j3, 32);
        ins4(ot0, oi0, q0, j0, q1, j1, q2, j2, q3, j3);
        ins4(ot1, oi1, q0, j0, q1, j1, q2, j2, q3, j3);
        ins4(ot2, oi2, q0, j0, q1, j1, q2, j2, q3, j3);
        ins4(ot3, oi3, q0, j0, q1, j1, q2, j2, q3, j3);
    }

    __syncthreads();
    if (wave_m == 1 && lane < 32) {
        int zr = wave_n * 32 + l31;
        mbuf[zr][0] = q0; mbuf[zr][1] = q1; mbuf[zr][2] = q2; mbuf[zr][3] = q3;
        mbuf[zr][4] = __int_as_float(j0); mbuf[zr][5] = __int_as_float(j1);
        mbuf[zr][6] = __int_as_float(j2); mbuf[zr][7] = __int_as_float(j3);
    }
    __syncthreads();
    if (wave_m == 0 && lane < 32) {
        int zr = wave_n * 32 + l31;
        ins4(mbuf[zr][0], __float_as_int(mbuf[zr][4]), q0, j0, q1, j1, q2, j2, q3, j3);
        ins4(mbuf[zr][1], __float_as_int(mbuf[zr][5]), q0, j0, q1, j1, q2, j2, q3, j3);
        ins4(mbuf[zr][2], __float_as_int(mbuf[zr][6]), q0, j0, q1, j1, q2, j2, q3, j3);
        ins4(mbuf[zr][3], __float_as_int(mbuf[zr][7]), q0, j0, q1, j1, q2, j2, q3, j3);
        float4 pa = make_float4(q0, q1, q2, q3);
        float4 pb = make_float4(__int_as_float(j0), __int_as_float(j1),
                                __int_as_float(j2), __int_as_float(j3));
        size_t base = ((size_t)(brow0 + zr) * 8 + jg) * 2;
        part[base] = pa;
        part[base + 1] = pb;
    }
}

// ---------------------------------------------------------------- fp64 rescore, wave-per-row
// z read from z32t (row-major fp32, coalesced). Shortlist slack 1.2e-4 (R5-validated).
__global__ void rescore_kernel(const float* __restrict__ z32t, const float* __restrict__ emb,
                               const float* __restrict__ enorm_g, const float* __restrict__ cnorm_g,
                               const float4* __restrict__ part, float* __restrict__ out,
                               int* __restrict__ ws_i0, int* __restrict__ hist,
                               double* __restrict__ t0sum) {
    const int tid  = threadIdx.x;
    const int lane = tid & 63, wid = tid >> 6;
    const int r = blockIdx.x * 4 + wid;       // 4096 blocks x 4 waves

    const int c4 = lane * 4;
    float4 zv = *(const float4*)(z32t + (size_t)r * 256 + c4);
    const double zv0 = (double)zv.x, zv1 = (double)zv.y, zv2 = (double)zv.z, zv3 = (double)zv.w;

    float m1 = FLT_MAX, m2 = FLT_MAX;
    for (int jg = 0; jg < 8; jg++) {
        float4 pa = part[((size_t)r * 8 + jg) * 2];
        if (pa.x < m1) { m2 = m1; m1 = pa.x; } else if (pa.x < m2) m2 = pa.x;
        if (pa.y < m1) { m2 = m1; m1 = pa.y; } else if (pa.y < m2) m2 = pa.y;
    }
    const float T = m2 + 1.2e-4f;
    const float C = cnorm_g[r];

    float bt0 = FLT_MAX, bt1 = FLT_MAX;
    int   bi0 = NE - 1, bi1 = NE - 1;
    bool  any = false;
    for (int jg = 0; jg < 8; jg++) {
        float4 pa = part[((size_t)r * 8 + jg) * 2];
        float4 pb = part[((size_t)r * 8 + jg) * 2 + 1];
        float tv[4] = {pa.x, pa.y, pa.z, pa.w};
        int   jv[4] = {__float_as_int(pb.x), __float_as_int(pb.y),
                       __float_as_int(pb.z), __float_as_int(pb.w)};
        for (int e = 0; e < 4; e++) {
            if (tv[e] <= T) {
                const int j = jv[e] & (NE - 1);
                float4 ev = *(const float4*)(emb + ((size_t)j << 8) + c4);
                double gl = zv0 * (double)ev.x + zv1 * (double)ev.y +
                            zv2 * (double)ev.z + zv3 * (double)ev.w;
#pragma unroll
                for (int m = 1; m < 64; m <<= 1) gl += __shfl_xor(gl, m);
                float g2 = (float)(2.0 * gl);
                float S = C + enorm_g[j];
                float tex = S - g2;
                if (tex < bt0 || (tex == bt0 && j < bi0)) {
                    bt1 = bt0; bi1 = bi0; bt0 = tex; bi0 = j;
                } else if (tex < bt1 || (tex == bt1 && j < bi1)) {
                    bt1 = tex; bi1 = j;
                }
                any = true;
            }
        }
    }
    if (!any) { bt0 = 0.f; bi0 = 0; bi1 = 0; }

    if (lane == 0) {
        out[OFF_I0 + r] = (float)bi0;
        out[OFF_I1 + r] = (float)bi1;
        ws_i0[r] = bi0;
        atomicAdd(&hist[bi0], 1);
    }
    __shared__ double red[4];
    if (lane == 0) red[wid] = (double)bt0;
    __syncthreads();
    if (tid == 0) atomicAdd(t0sum, (red[0] + red[1]) + (red[2] + red[3]));
}

// ---------------------------------------------------------------- z_q gather (LDS transpose)
// Block = 64 rows. Gather emb rows coalesced -> LDS; write (c, hw)-contiguous.
__global__ void zq_kernel(const float* __restrict__ emb, const int* __restrict__ ws_i0,
                          float* __restrict__ out) {
    __shared__ float zt[64][65];
    const int tid = threadIdx.x;          // 256
    const int r0  = blockIdx.x * 64;      // 256 blocks
    const int b   = r0 >> 10;
    const int hw0 = r0 & 1023;
    const int kb  = blockIdx.y;           // 4 chunks of 64 channels
#pragma unroll
    for (int p = 0; p < 4; p++) {
        int q = p * 256 + tid;            // 1024 quads: 64 rows x 16
        int row = q >> 4, co = (q & 15) * 4;
        int idx = ws_i0[r0 + row] & (NE - 1);
        float4 v = *(const float4*)(emb + ((size_t)idx << 8) + kb * 64 + co);
        zt[row][co + 0] = v.x; zt[row][co + 1] = v.y;
        zt[row][co + 2] = v.z; zt[row][co + 3] = v.w;
    }
    __syncthreads();
#pragma unroll
    for (int p = 0; p < 4; p++) {
        int q = p * 256 + tid;            // 1024: 64 c x 16 hw-quads
        int c = q >> 4, h4 = (q & 15) * 4;
        float4 v = make_float4(zt[h4 + 0][c], zt[h4 + 1][c], zt[h4 + 2][c], zt[h4 + 3][c]);
        *(float4*)(out + OFF_ZQ + (((size_t)b * 256 + kb * 64 + c) << 10) + hw0 + h4) = v;
    }
}

// ---------------------------------------------------------------- finalize
__global__ void finalize_kernel(const int* __restrict__ hist, const double* __restrict__ t0sum,
                                float* __restrict__ out) {
    __shared__ float red[256];
    float s = 0.f;
    for (int j = threadIdx.x; j < NE; j += 256) {
        float p = (float)hist[j] * (1.0f / 16384.0f);
        s += p * logf(p + 1e-10f);
    }
    red[threadIdx.x] = s;
    __syncthreads();
    for (int m = 128; m; m >>= 1) {
        if (threadIdx.x < m) red[threadIdx.x] += red[threadIdx.x + m];
        __syncthreads();
    }
    if (threadIdx.x == 0) {
        out[OFF_PERP] = expf(-red[0]);
        out[OFF_LOSS] = 1.25f * (float)(t0sum[0] * (1.0 / 4194304.0));
    }
}

extern "C" void kernel_launch(void* const* d_in, const int* in_sizes, int n_in,
                              void* d_out, int out_size, void* d_ws, size_t ws_size,
                              hipStream_t stream) {
    const float* z   = (const float*)d_in[0];
    const float* emb = (const float*)d_in[1];
    float* out = (float*)d_out;
    float* ws  = (float*)d_ws;

    int*    ws_i0    = (int*)ws + WS_I0;
    int*    ws_hist  = (int*)ws + WS_HIST;
    float*  ws_enorm = ws + WS_ENORM;
    float*  ws_cnorm = ws + WS_CNORM;
    double* ws_t0sum = (double*)(ws + WS_T0SUM);

    float* scr = out + OFF_ONEHOT + 2;   // 16B-aligned scratch in one-hot region
    _Float16* z16 = (_Float16*)(scr + SCR_Z16);
    _Float16* e16 = (_Float16*)(scr + SCR_E16);
    float4* part  = (float4*)(scr + SCR_PART);
    float*  z32t  = scr + SCR_Z32T;

    hipLaunchKernelGGL(zero_ws_kernel, dim3(194), dim3(256), 0, stream, ws);
    hipLaunchKernelGGL(enorm_kernel, dim3(512), dim3(256), 0, stream, emb, ws_enorm);
    hipLaunchKernelGGL(cnorm_kernel, dim3(1024), dim3(256), 0, stream, z, ws_cnorm);
    hipLaunchKernelGGL(split_z_kernel, dim3(256, 4), dim3(256), 0, stream, z, z16, z32t);
    hipLaunchKernelGGL(split_e_kernel, dim3(1024), dim3(256), 0, stream, emb, e16);
    hipLaunchKernelGGL(mfma_top4_kernel, dim3(8, 128), dim3(512), 0, stream,
                       e16, z16, ws_enorm, ws_cnorm, part);
    hipLaunchKernelGGL(rescore_kernel, dim3(4096), dim3(256), 0, stream,
                       z32t, emb, ws_enorm, ws_cnorm, part, out, ws_i0, ws_hist, ws_t0sum);
    hipLaunchKernelGGL(zero_onehot_kernel, dim3(4096), dim3(1024), 0, stream, out);
    hipLaunchKernelGGL(scatter_ones_kernel, dim3(64), dim3(256), 0, stream, ws_i0, out);
    hipLaunchKernelGGL(zq_kernel, dim3(256, 4), dim3(256), 0, stream, emb, ws_i0, out);
    hipLaunchKernelGGL(finalize_kernel, dim3(1), dim3(256), 0, stream,
                       ws_hist, ws_t0sum, out);
}

// Round 8
// 1159.620 us; speedup vs baseline: 1.1575x; 1.1575x over previous
//
#include <hip/hip_runtime.h>
#include <cfloat>
#include <cstdint>
#include <cstddef>

// Problem constants
#define M_ROWS 16384
#define NE     8192
#define KD     256

// d_out layout (float elements)
#define OFF_LOSS   0ULL
#define OFF_ZQ     1ULL
#define OFF_PERP   4194305ULL
#define OFF_ONEHOT 4194306ULL
#define OFF_I0     138412034ULL
#define OFF_I1     138428418ULL

// Scratch inside the one-hot output region (zeroed AFTER use).
// base = out + OFF_ONEHOT + 2 (16B-aligned). Offsets in floats:
#define SCR_Z16  0ULL         // fp16[16384][256] BK32-swizzled = 8 MB
#define SCR_E16  2097152ULL   // fp16[8192][256] BK32-swizzled (x256 scale) = 4 MB
#define SCR_Z32T 3145728ULL   // fp32[16384][256] row-major transposed z = 16 MB
#define SCR_PART 7340032ULL   // float4[16384][64] = 16 MB

// d_ws layout (4-byte units)
#define WS_I0    0        // int[16384]
#define WS_HIST  16384    // int[8192]
#define WS_ENORM 24576    // float[8192]
#define WS_CNORM 32768    // float[16384]
#define WS_T0SUM 49152    // double (2 slots, 8B-aligned)
#define WS_TOTAL 49154

typedef _Float16 fp16x8 __attribute__((ext_vector_type(8)));
typedef float    floatx16 __attribute__((ext_vector_type(16)));

// ---------------------------------------------------------------- zero ws
__global__ void zero_ws_kernel(float* __restrict__ ws) {
    int i = blockIdx.x * 256 + threadIdx.x;
    if (i < WS_TOTAL) ws[i] = 0.0f;
}

// ------------------------------------------------- zero one-hot region (537 MB)
__global__ void zero_onehot_kernel(float* __restrict__ out) {
    size_t tidg = (size_t)blockIdx.x * 1024 + threadIdx.x;   // 4096 x 1024
    float4* base = (float4*)(out + OFF_ONEHOT + 2);
    const float4 zz = make_float4(0.f, 0.f, 0.f, 0.f);
#pragma unroll
    for (int i = 0; i < 8; i++) {
        size_t q = tidg + (size_t)i * 4194304ULL;
        if (q < 33554431ULL) base[q] = zz;
    }
    if (tidg == 0) {
        out[OFF_ONEHOT + 0] = 0.f;
        out[OFF_ONEHOT + 1] = 0.f;
        out[OFF_ONEHOT + 134217726ULL] = 0.f;
        out[OFF_ONEHOT + 134217727ULL] = 0.f;
    }
}

// ---------------------------------------------------------------- scatter ones
__global__ void scatter_ones_kernel(const int* __restrict__ ws_i0, float* __restrict__ out) {
    int r = blockIdx.x * 256 + threadIdx.x;   // 64 x 256
    int j = ws_i0[r] & (NE - 1);
    out[OFF_ONEHOT + (size_t)r * NE + j] = 1.0f;
}

// ------------------------------------------------------------------------
// numpy float32 pairwise sum over 256 elements, emulated exactly (validated R2)
__device__ __forceinline__ float pairwise16(const float* sq, int lane16) {
    const int h = lane16 >> 3;
    const int j = lane16 & 7;
    float r = sq[h * 128 + j];
#pragma unroll
    for (int i = 1; i < 16; i++) r = r + sq[h * 128 + i * 8 + j];
    float s = r + __shfl_xor(r, 1);
    s = s + __shfl_xor(s, 2);
    s = s + __shfl_xor(s, 4);
    s = s + __shfl_xor(s, 8);
    return s;
}

// ---------------------------------------------------------------- E_j emulation
__global__ void enorm_kernel(const float* __restrict__ emb, float* __restrict__ enorm) {
    __shared__ float sq[16][257];
    const int tid = threadIdx.x;
    const int row0 = blockIdx.x * 16;
#pragma unroll
    for (int p = 0; p < 4; p++) {
        int q = p * 256 + tid;
        int rl = q >> 6, kq = q & 63;
        float4 v = *(const float4*)(emb + (size_t)(row0 + rl) * KD + kq * 4);
        sq[rl][kq * 4 + 0] = v.x * v.x;
        sq[rl][kq * 4 + 1] = v.y * v.y;
        sq[rl][kq * 4 + 2] = v.z * v.z;
        sq[rl][kq * 4 + 3] = v.w * v.w;
    }
    __syncthreads();
    const int rl = tid >> 4, lane16 = tid & 15;
    float s = pairwise16(&sq[rl][0], lane16);
    if (lane16 == 0) enorm[row0 + rl] = s;
}

// ---------------------------------------------------------------- C_r emulation
__global__ void cnorm_kernel(const float* __restrict__ z, float* __restrict__ cnorm) {
    __shared__ float sq[16][257];
    const int tid = threadIdx.x;
    const int r0  = blockIdx.x * 16;
    const int b   = r0 >> 10;
    const int hw0 = r0 & 1023;
    const float* zb = z + ((size_t)b << 18) + hw0;
#pragma unroll
    for (int p = 0; p < 4; p++) {
        int q = p * 256 + tid;
        int c = q >> 2, hq = q & 3;
        float4 v = *(const float4*)(zb + ((size_t)c << 10) + hq * 4);
        sq[hq * 4 + 0][c] = v.x * v.x;
        sq[hq * 4 + 1][c] = v.y * v.y;
        sq[hq * 4 + 2][c] = v.z * v.z;
        sq[hq * 4 + 3][c] = v.w * v.w;
    }
    __syncthreads();
    const int rl = tid >> 4, lane16 = tid & 15;
    float s = pairwise16(&sq[rl][0], lane16);
    if (lane16 == 0) cnorm[r0 + rl] = s;
}

// ---------------------------------------------------------------- z -> fp16 BK32-swizzled + fp32 transposed
// 16B-unit index: kb = k>>5 (0..7), k8 = (k>>3)&3:
//   unit = ((r>>7)*8 + kb)*512 + (r&127)*4 + (k8 ^ (r&3))
// One 128-row x 32-k tile = 512 contiguous units (8 KB).
__global__ void split_z_kernel(const float* __restrict__ z, _Float16* __restrict__ z16,
                               float* __restrict__ z32t) {
    __shared__ float tile[64][65];
    const int tid = threadIdx.x;            // 256
    const int r0  = blockIdx.x * 64;        // 256 row-blocks
    const int kbig = blockIdx.y;            // 4 k-blocks of 64
    const int b   = r0 >> 10;
    const int hw0 = r0 & 1023;
#pragma unroll
    for (int p = 0; p < 4; p++) {
        int q = p * 256 + tid;
        int cl = q >> 4, hq = q & 15;
        float4 v = *(const float4*)(z + ((size_t)b << 18) + (size_t)(kbig * 64 + cl) * 1024 + hw0 + hq * 4);
        tile[hq * 4 + 0][cl] = v.x;
        tile[hq * 4 + 1][cl] = v.y;
        tile[hq * 4 + 2][cl] = v.z;
        tile[hq * 4 + 3][cl] = v.w;
    }
    __syncthreads();
#pragma unroll
    for (int p = 0; p < 2; p++) {
        int u = p * 256 + tid;              // 512 octets: 64 rows x 8 k8l
        int row = u >> 3, k8l = u & 7;
        int r = r0 + row;
        fp16x8 vh;
#pragma unroll
        for (int e = 0; e < 8; e++) vh[e] = (_Float16)tile[row][k8l * 8 + e];
        int kb = kbig * 2 + (k8l >> 2);
        int k8 = k8l & 3;
        size_t unit = ((size_t)(r >> 7) * 8 + kb) * 512 + (size_t)(r & 127) * 4 + (k8 ^ (r & 3));
        *(fp16x8*)(z16 + unit * 8) = vh;
    }
    // fp32 transposed row-major copy for rescore (coalesced)
#pragma unroll
    for (int p = 0; p < 4; p++) {
        int q = p * 256 + tid;              // 1024 quads: 64 rows x 16
        int row = q >> 4, co = (q & 15) * 4;
        float4 v = make_float4(tile[row][co], tile[row][co + 1], tile[row][co + 2], tile[row][co + 3]);
        *(float4*)(z32t + (size_t)(r0 + row) * 256 + kbig * 64 + co) = v;
    }
}

// ---------------------------------------------------------------- e -> fp16*256 (same layout)
__global__ void split_e_kernel(const float* __restrict__ emb, _Float16* __restrict__ e16) {
    int u = blockIdx.x * 256 + threadIdx.x;   // 1024 x 256 = 262144 octets
    size_t go = (size_t)u * 8;                // = code*256 + k8g*8
    float4 v0 = *(const float4*)(emb + go);
    float4 v1 = *(const float4*)(emb + go + 4);
    float x[8] = {v0.x, v0.y, v0.z, v0.w, v1.x, v1.y, v1.z, v1.w};
    fp16x8 vh;
#pragma unroll
    for (int e = 0; e < 8; e++) vh[e] = (_Float16)(x[e] * 256.0f);  // exact pow2 scale
    int code = u >> 5, k8g = u & 31;
    int kb = k8g >> 2, k8 = k8g & 3;
    size_t unit = ((size_t)(code >> 7) * 8 + kb) * 512 + (size_t)(code & 127) * 4 + (k8 ^ (code & 3));
    *(fp16x8*)(e16 + unit * 8) = vh;
}

// ---------------------------------------------------------------- helpers
__device__ __forceinline__ fp16x8 frag_ld(const _Float16* lds, int rc, int ku) {
    int slot = rc * 4 + (ku ^ (rc & 3));
    return *(const fp16x8*)(lds + slot * 8);
}

#define MFMA(d, a, b) d = __builtin_amdgcn_mfma_f32_32x32x16_f16(a, b, d, 0, 0, 0)

__device__ __forceinline__ void ins2(float t, int i, float& t0, int& i0, float& t1, int& i1) {
    if (t < t0 || (t == t0 && i < i0)) { t1 = t0; i1 = i0; t0 = t; i0 = i; }
    else if (t < t1 || (t == t1 && i < i1)) { t1 = t; i1 = i; }
}

// ---------------------------------------------------------------- MFMA top-2 (m97-regime)
// 128 codes x 128 zrows per block; BK=32, 8 K-iters; plain-load + ds_write dbuf;
// 3 blocks/CU for continuous VMEM-queue occupancy. t~ = fmaf(-2/256, acc, C+E).
__launch_bounds__(256, 3)
__global__ void mfma_top2_kernel(const _Float16* __restrict__ e16, const _Float16* __restrict__ z16,
                                 const float* __restrict__ enorm_g, const float* __restrict__ cnorm_g,
                                 float4* __restrict__ part) {
    __shared__ _Float16 As[2][4096];   // 2 x 8 KB
    __shared__ _Float16 Bs[2][4096];
    __shared__ float enb[128];
    __shared__ float mbuf[128][4];

    const int tid = threadIdx.x;
    const int lane = tid & 63, wid = tid >> 6;
    const int l31 = lane & 31, half = lane >> 5;
    const int wave_m = wid & 1, wave_n = wid >> 1;
    const int mtile = blockIdx.x;          // 64
    const int ntile = blockIdx.y;          // 128

    const float4* Ap = (const float4*)(e16 + (size_t)mtile * 8 * 512 * 8);
    const float4* Bp = (const float4*)(z16 + (size_t)ntile * 8 * 512 * 8);

    if (tid < 128) enb[tid] = enorm_g[mtile * 128 + tid];
    float Cn[2];
    Cn[0] = cnorm_g[ntile * 128 + wave_n * 64 + l31];
    Cn[1] = cnorm_g[ntile * 128 + wave_n * 64 + 32 + l31];

    const int rcA0 = wave_m * 64 + l31, rcA1 = rcA0 + 32;
    const int rcB0 = wave_n * 64 + l31, rcB1 = rcB0 + 32;

    // prologue: kb=0 into buffer 0
    {
        float4 ra0 = Ap[tid], ra1 = Ap[256 + tid];
        float4 rb0 = Bp[tid], rb1 = Bp[256 + tid];
        ((float4*)As[0])[tid] = ra0; ((float4*)As[0])[256 + tid] = ra1;
        ((float4*)Bs[0])[tid] = rb0; ((float4*)Bs[0])[256 + tid] = rb1;
    }
    __syncthreads();

    floatx16 acc00 = (floatx16)0.f, acc01 = (floatx16)0.f,
             acc10 = (floatx16)0.f, acc11 = (floatx16)0.f;

    for (int kb = 0; kb < 8; kb++) {
        const int cur = kb & 1;
        float4 ra0, ra1, rb0, rb1;
        if (kb < 7) {   // prefetch next tile into registers (latency overlapped)
            const int nb = (kb + 1) * 512;
            ra0 = Ap[nb + tid]; ra1 = Ap[nb + 256 + tid];
            rb0 = Bp[nb + tid]; rb1 = Bp[nb + 256 + tid];
        }
#pragma unroll
        for (int ks = 0; ks < 2; ks++) {
            const int ku = ks * 2 + half;
            fp16x8 a0 = frag_ld(As[cur], rcA0, ku);
            fp16x8 a1 = frag_ld(As[cur], rcA1, ku);
            fp16x8 b0 = frag_ld(Bs[cur], rcB0, ku);
            fp16x8 b1 = frag_ld(Bs[cur], rcB1, ku);
            MFMA(acc00, a0, b0);
            MFMA(acc01, a0, b1);
            MFMA(acc10, a1, b0);
            MFMA(acc11, a1, b1);
        }
        if (kb < 7) {   // write into the *other* buffer: no race with cur readers
            ((float4*)As[cur ^ 1])[tid] = ra0; ((float4*)As[cur ^ 1])[256 + tid] = ra1;
            ((float4*)Bs[cur ^ 1])[tid] = rb0; ((float4*)Bs[cur ^ 1])[256 + tid] = rb1;
        }
        __syncthreads();
    }

    // fold: C/D 32x32: col = lane&31 (zrow), row = (reg&3)+8*(reg>>2)+4*half (code)
    float t0s[2] = {FLT_MAX, FLT_MAX}, t1s[2] = {FLT_MAX, FLT_MAX};
    int   i0s[2] = {0x7fffffff, 0x7fffffff}, i1s[2] = {0x7fffffff, 0x7fffffff};
#pragma unroll
    for (int mt = 0; mt < 2; mt++) {
#pragma unroll
        for (int reg = 0; reg < 16; reg++) {
            const int rl = (reg & 3) + 8 * (reg >> 2) + 4 * half;
            const int cloc = wave_m * 64 + mt * 32 + rl;
            const int code = mtile * 128 + cloc;
            const float E = enb[cloc];
            float g0 = (mt == 0) ? acc00[reg] : acc10[reg];
            float g1 = (mt == 0) ? acc01[reg] : acc11[reg];
            ins2(fmaf(-0.0078125f, g0, Cn[0] + E), code, t0s[0], i0s[0], t1s[0], i1s[0]);
            ins2(fmaf(-0.0078125f, g1, Cn[1] + E), code, t0s[1], i0s[1], t1s[1], i1s[1]);
        }
    }
    // half-lane merge (same zrow, complementary code rows)
#pragma unroll
    for (int s = 0; s < 2; s++) {
        float o0 = __shfl_xor(t0s[s], 32), o1 = __shfl_xor(t1s[s], 32);
        int  oi0 = __shfl_xor(i0s[s], 32), oi1 = __shfl_xor(i1s[s], 32);
        ins2(o0, oi0, t0s[s], i0s[s], t1s[s], i1s[s]);
        ins2(o1, oi1, t0s[s], i0s[s], t1s[s], i1s[s]);
    }
    __syncthreads();
    if (wave_m == 1 && lane < 32) {
#pragma unroll
        for (int s = 0; s < 2; s++) {
            int zr = wave_n * 64 + s * 32 + l31;
            mbuf[zr][0] = t0s[s]; mbuf[zr][1] = t1s[s];
            mbuf[zr][2] = __int_as_float(i0s[s]); mbuf[zr][3] = __int_as_float(i1s[s]);
        }
    }
    __syncthreads();
    if (wave_m == 0 && lane < 32) {
#pragma unroll
        for (int s = 0; s < 2; s++) {
            int zr = wave_n * 64 + s * 32 + l31;
            ins2(mbuf[zr][0], __float_as_int(mbuf[zr][2]), t0s[s], i0s[s], t1s[s], i1s[s]);
            ins2(mbuf[zr][1], __float_as_int(mbuf[zr][3]), t0s[s], i0s[s], t1s[s], i1s[s]);
            float4 o;
            o.x = t0s[s]; o.y = t1s[s];
            o.z = __int_as_float(i0s[s]); o.w = __int_as_float(i1s[s]);
            part[(size_t)(ntile * 128 + zr) * 64 + mtile] = o;
        }
    }
}

// ---------------------------------------------------------------- fp64 rescore, wave-per-row
// 64 per-M-tile top-2 entries/row; shortlist slack 1.2e-4 (R5-validated).
__global__ void rescore_kernel(const float* __restrict__ z32t, const float* __restrict__ emb,
                               const float* __restrict__ enorm_g, const float* __restrict__ cnorm_g,
                               const float4* __restrict__ part, float* __restrict__ out,
                               int* __restrict__ ws_i0, int* __restrict__ hist,
                               double* __restrict__ t0sum) {
    const int tid  = threadIdx.x;
    const int lane = tid & 63, wid = tid >> 6;
    const int r = blockIdx.x * 4 + wid;       // 4096 blocks x 4 waves

    const int c4 = lane * 4;
    float4 zv = *(const float4*)(z32t + (size_t)r * 256 + c4);
    const double zv0 = (double)zv.x, zv1 = (double)zv.y, zv2 = (double)zv.z, zv3 = (double)zv.w;

    float m1 = FLT_MAX, m2 = FLT_MAX;
    for (int g = 0; g < 64; g++) {
        float4 p = part[(size_t)r * 64 + g];
        if (p.x < m1) { m2 = m1; m1 = p.x; } else if (p.x < m2) m2 = p.x;
        if (p.y < m1) { m2 = m1; m1 = p.y; } else if (p.y < m2) m2 = p.y;
    }
    const float T = m2 + 1.2e-4f;
    const float C = cnorm_g[r];

    float bt0 = FLT_MAX, bt1 = FLT_MAX;
    int   bi0 = NE - 1, bi1 = NE - 1;
    for (int g = 0; g < 64; g++) {
        float4 p = part[(size_t)r * 64 + g];
        float tv[2] = {p.x, p.y};
        int   jv[2] = {__float_as_int(p.z), __float_as_int(p.w)};
#pragma unroll
        for (int e = 0; e < 2; e++) {
            if (tv[e] <= T) {            // uniform across wave
                const int j = jv[e] & (NE - 1);
                float4 ev = *(const float4*)(emb + ((size_t)j << 8) + c4);
                double gl = zv0 * (double)ev.x + zv1 * (double)ev.y +
                            zv2 * (double)ev.z + zv3 * (double)ev.w;
#pragma unroll
                for (int m = 1; m < 64; m <<= 1) gl += __shfl_xor(gl, m);
                float g2 = (float)(2.0 * gl);
                float S = C + enorm_g[j];
                float tex = S - g2;
                if (tex < bt0 || (tex == bt0 && j < bi0)) {
                    bt1 = bt0; bi1 = bi0; bt0 = tex; bi0 = j;
                } else if (tex < bt1 || (tex == bt1 && j < bi1)) {
                    bt1 = tex; bi1 = j;
                }
            }
        }
    }

    if (lane == 0) {
        out[OFF_I0 + r] = (float)bi0;
        out[OFF_I1 + r] = (float)bi1;
        ws_i0[r] = bi0;
        atomicAdd(&hist[bi0], 1);
    }
    __shared__ double red[4];
    if (lane == 0) red[wid] = (double)bt0;
    __syncthreads();
    if (tid == 0) atomicAdd(t0sum, (red[0] + red[1]) + (red[2] + red[3]));
}

// ---------------------------------------------------------------- z_q gather (LDS transpose)
__global__ void zq_kernel(const float* __restrict__ emb, const int* __restrict__ ws_i0,
                          float* __restrict__ out) {
    __shared__ float zt[64][65];
    const int tid = threadIdx.x;          // 256
    const int r0  = blockIdx.x * 64;      // 256 blocks
    const int b   = r0 >> 10;
    const int hw0 = r0 & 1023;
    const int kb  = blockIdx.y;           // 4 chunks of 64 channels
#pragma unroll
    for (int p = 0; p < 4; p++) {
        int q = p * 256 + tid;            // 1024 quads: 64 rows x 16
        int row = q >> 4, co = (q & 15) * 4;
        int idx = ws_i0[r0 + row] & (NE - 1);
        float4 v = *(const float4*)(emb + ((size_t)idx << 8) + kb * 64 + co);
        zt[row][co + 0] = v.x; zt[row][co + 1] = v.y;
        zt[row][co + 2] = v.z; zt[row][co + 3] = v.w;
    }
    __syncthreads();
#pragma unroll
    for (int p = 0; p < 4; p++) {
        int q = p * 256 + tid;            // 1024: 64 c x 16 hw-quads
        int c = q >> 4, h4 = (q & 15) * 4;
        float4 v = make_float4(zt[h4 + 0][c], zt[h4 + 1][c], zt[h4 + 2][c], zt[h4 + 3][c]);
        *(float4*)(out + OFF_ZQ + (((size_t)b * 256 + kb * 64 + c) << 10) + hw0 + h4) = v;
    }
}

// ---------------------------------------------------------------- finalize
__global__ void finalize_kernel(const int* __restrict__ hist, const double* __restrict__ t0sum,
                                float* __restrict__ out) {
    __shared__ float red[256];
    float s = 0.f;
    for (int j = threadIdx.x; j < NE; j += 256) {
        float p = (float)hist[j] * (1.0f / 16384.0f);
        s += p * logf(p + 1e-10f);
    }
    red[threadIdx.x] = s;
    __syncthreads();
    for (int m = 128; m; m >>= 1) {
        if (threadIdx.x < m) red[threadIdx.x] += red[threadIdx.x + m];
        __syncthreads();
    }
    if (threadIdx.x == 0) {
        out[OFF_PERP] = expf(-red[0]);
        out[OFF_LOSS] = 1.25f * (float)(t0sum[0] * (1.0 / 4194304.0));
    }
}

extern "C" void kernel_launch(void* const* d_in, const int* in_sizes, int n_in,
                              void* d_out, int out_size, void* d_ws, size_t ws_size,
                              hipStream_t stream) {
    const float* z   = (const float*)d_in[0];
    const float* emb = (const float*)d_in[1];
    float* out = (float*)d_out;
    float* ws  = (float*)d_ws;

    int*    ws_i0    = (int*)ws + WS_I0;
    int*    ws_hist  = (int*)ws + WS_HIST;
    float*  ws_enorm = ws + WS_ENORM;
    float*  ws_cnorm = ws + WS_CNORM;
    double* ws_t0sum = (double*)(ws + WS_T0SUM);

    float* scr = out + OFF_ONEHOT + 2;   // 16B-aligned scratch in one-hot region
    _Float16* z16 = (_Float16*)(scr + SCR_Z16);
    _Float16* e16 = (_Float16*)(scr + SCR_E16);
    float*  z32t  = scr + SCR_Z32T;
    float4* part  = (float4*)(scr + SCR_PART);

    hipLaunchKernelGGL(zero_ws_kernel, dim3(194), dim3(256), 0, stream, ws);
    hipLaunchKernelGGL(enorm_kernel, dim3(512), dim3(256), 0, stream, emb, ws_enorm);
    hipLaunchKernelGGL(cnorm_kernel, dim3(1024), dim3(256), 0, stream, z, ws_cnorm);
    hipLaunchKernelGGL(split_z_kernel, dim3(256, 4), dim3(256), 0, stream, z, z16, z32t);
    hipLaunchKernelGGL(split_e_kernel, dim3(1024), dim3(256), 0, stream, emb, e16);
    hipLaunchKernelGGL(mfma_top2_kernel, dim3(64, 128), dim3(256), 0, stream,
                       e16, z16, ws_enorm, ws_cnorm, part);
    hipLaunchKernelGGL(rescore_kernel, dim3(4096), dim3(256), 0, stream,
                       z32t, emb, ws_enorm, ws_cnorm, part, out, ws_i0, ws_hist, ws_t0sum);
    hipLaunchKernelGGL(zero_onehot_kernel, dim3(4096), dim3(1024), 0, stream, out);
    hipLaunchKernelGGL(scatter_ones_kernel, dim3(64), dim3(256), 0, stream, ws_i0, out);
    hipLaunchKernelGGL(zq_kernel, dim3(256, 4), dim3(256), 0, stream, emb, ws_i0, out);
    hipLaunchKernelGGL(finalize_kernel, dim3(1), dim3(256), 0, stream,
                       ws_hist, ws_t0sum, out);
}

// Round 9
// 1073.635 us; speedup vs baseline: 1.2502x; 1.0801x over previous
//
#include <hip/hip_runtime.h>
#include <cfloat>
#include <cstdint>
#include <cstddef>

// Problem constants
#define M_ROWS 16384
#define NE     8192
#define KD     256

// d_out layout (float elements)
#define OFF_LOSS   0ULL
#define OFF_ZQ     1ULL
#define OFF_PERP   4194305ULL
#define OFF_ONEHOT 4194306ULL
#define OFF_I0     138412034ULL
#define OFF_I1     138428418ULL

// Scratch inside the one-hot output region (zeroed AFTER use).
// base = out + OFF_ONEHOT + 2 (16B-aligned). Offsets in floats:
#define SCR_Z16  0ULL         // fp16[16384][256] BK32-swizzled = 8 MB
#define SCR_E16  2097152ULL   // fp16[8192][256] BK32-swizzled (x256 scale) = 4 MB
#define SCR_Z32T 3145728ULL   // fp32[16384][256] row-major transposed z = 16 MB
#define SCR_PART 7340032ULL   // float4[16384][64] = 16 MB

// d_ws layout (4-byte units)
#define WS_I0    0        // int[16384]
#define WS_HIST  16384    // int[8192]
#define WS_ENORM 24576    // float[8192]
#define WS_CNORM 32768    // float[16384]
#define WS_T0SUM 49152    // double (2 float slots, 8B-aligned)
#define WS_TOTAL 49154

typedef _Float16 fp16x8 __attribute__((ext_vector_type(8)));
typedef float    floatx16 __attribute__((ext_vector_type(16)));

// ------------------------------------------------- zero one-hot region (537 MB)
__global__ void zero_onehot_kernel(float* __restrict__ out) {
    size_t tidg = (size_t)blockIdx.x * 1024 + threadIdx.x;   // 4096 x 1024
    float4* base = (float4*)(out + OFF_ONEHOT + 2);
    const float4 zz = make_float4(0.f, 0.f, 0.f, 0.f);
#pragma unroll
    for (int i = 0; i < 8; i++) {
        size_t q = tidg + (size_t)i * 4194304ULL;
        if (q < 33554431ULL) base[q] = zz;
    }
    if (tidg == 0) {
        out[OFF_ONEHOT + 0] = 0.f;
        out[OFF_ONEHOT + 1] = 0.f;
        out[OFF_ONEHOT + 134217726ULL] = 0.f;
        out[OFF_ONEHOT + 134217727ULL] = 0.f;
    }
}

// ---------------------------------------------------------------- scatter ones
__global__ void scatter_ones_kernel(const int* __restrict__ ws_i0, float* __restrict__ out) {
    int r = blockIdx.x * 256 + threadIdx.x;   // 64 x 256
    int j = ws_i0[r] & (NE - 1);
    out[OFF_ONEHOT + (size_t)r * NE + j] = 1.0f;
}

// ------------------------------------------------------------------------
// numpy float32 pairwise sum of squares over 256 elements (R2-validated
// structure); __fmul_rn/__fadd_rn forbid contraction, matching np exactly.
__device__ __forceinline__ float pairwise16_sq(const float* row, int lane16) {
    const int h = lane16 >> 3, j = lane16 & 7;
    const float* p = row + h * 128 + j;
    float x = p[0];
    float r = __fmul_rn(x, x);
#pragma unroll
    for (int i = 1; i < 16; i++) {
        float y = p[i * 8];
        r = __fadd_rn(r, __fmul_rn(y, y));
    }
    float s = __fadd_rn(r, __shfl_xor(r, 1));
    s = __fadd_rn(s, __shfl_xor(s, 2));
    s = __fadd_rn(s, __shfl_xor(s, 4));
    s = __fadd_rn(s, __shfl_xor(s, 8));
    return s;
}

// ---------------------------------------------------------------- e -> e16 + enorm + zero hist
// e16 layout (16B units): unit = ((code>>7)*8 + kb)*512 + (code&127)*4 + (k8 ^ (code&3)),
// k = kb*32 + k8*8 + e.  (identical to R8 producer formula)
__global__ void split_e_kernel(const float* __restrict__ emb, _Float16* __restrict__ e16,
                               float* __restrict__ enorm, int* __restrict__ hist,
                               float* __restrict__ wsf) {
    __shared__ float ef[16][261];
    const int tid = threadIdx.x;          // 256
    const int row0 = blockIdx.x * 16;     // 512 blocks
#pragma unroll
    for (int p = 0; p < 4; p++) {
        int q = p * 256 + tid;
        int rl = q >> 6, kq = q & 63;
        float4 v = *(const float4*)(emb + (size_t)(row0 + rl) * KD + kq * 4);
        ef[rl][kq * 4 + 0] = v.x; ef[rl][kq * 4 + 1] = v.y;
        ef[rl][kq * 4 + 2] = v.z; ef[rl][kq * 4 + 3] = v.w;
    }
    __syncthreads();
    // e16 (x256 exact pow2 scale; avoids fp16 subnormals)
#pragma unroll
    for (int p = 0; p < 2; p++) {
        int u = p * 256 + tid;            // 512 units: 16 codes x 32 octets
        int rl = u >> 5, k8g = u & 31;
        int code = row0 + rl;
        fp16x8 vh;
#pragma unroll
        for (int e = 0; e < 8; e++) vh[e] = (_Float16)(ef[rl][k8g * 8 + e] * 256.0f);
        int kb = k8g >> 2, k8 = k8g & 3;
        size_t unit = ((size_t)(code >> 7) * 8 + kb) * 512 + (size_t)(code & 127) * 4 + (k8 ^ (code & 3));
        *(fp16x8*)(e16 + unit * 8) = vh;
    }
    // enorm (exact np pairwise)
    {
        int rl = tid >> 4, lane16 = tid & 15;
        float s = pairwise16_sq(&ef[rl][0], lane16);
        if (lane16 == 0) enorm[row0 + rl] = s;
    }
    // zero hist + t0sum (rescore accumulators)
    if (blockIdx.x < 32) hist[blockIdx.x * 256 + tid] = 0;
    if (blockIdx.x == 32 && tid < 2) wsf[WS_T0SUM + tid] = 0.0f;
}

// ---------------------------------------------------------------- z -> z16 + z32t + cnorm (fused)
__global__ void split_z_kernel(const float* __restrict__ z, _Float16* __restrict__ z16,
                               float* __restrict__ z32t, float* __restrict__ cnorm) {
    __shared__ float zf[64][261];   // 66.8 KB: 64 rows x 256 k (+pad)
    const int tid = threadIdx.x;            // 256
    const int r0  = blockIdx.x * 64;        // 256 row-blocks
    const int b   = r0 >> 10;
    const int hw0 = r0 & 1023;
    const float* zb = z + ((size_t)b << 18) + hw0;
#pragma unroll
    for (int p = 0; p < 16; p++) {
        int q = p * 256 + tid;              // 4096 quads: 256 c x 16 hw-quads
        int c = q >> 4, hq = q & 15;
        float4 v = *(const float4*)(zb + ((size_t)c << 10) + hq * 4);
        zf[hq * 4 + 0][c] = v.x; zf[hq * 4 + 1][c] = v.y;
        zf[hq * 4 + 2][c] = v.z; zf[hq * 4 + 3][c] = v.w;
    }
    __syncthreads();
    // cnorm (exact np pairwise), 4 passes x 16 rows
#pragma unroll
    for (int rr = 0; rr < 4; rr++) {
        int row = rr * 16 + (tid >> 4);
        float s = pairwise16_sq(&zf[row][0], tid & 15);
        if ((tid & 15) == 0) cnorm[r0 + row] = s;
    }
    // z16 swizzled
#pragma unroll
    for (int p = 0; p < 8; p++) {
        int u = p * 256 + tid;              // 2048 units: 64 rows x 32 octets
        int row = u >> 5, k8g = u & 31;
        int r = r0 + row;
        fp16x8 vh;
#pragma unroll
        for (int e = 0; e < 8; e++) vh[e] = (_Float16)zf[row][k8g * 8 + e];
        int kb = k8g >> 2, k8 = k8g & 3;
        size_t unit = ((size_t)(r >> 7) * 8 + kb) * 512 + (size_t)(r & 127) * 4 + (k8 ^ (r & 3));
        *(fp16x8*)(z16 + unit * 8) = vh;
    }
    // z32t row-major fp32 (for rescore)
#pragma unroll
    for (int p = 0; p < 16; p++) {
        int q = p * 256 + tid;              // 4096 quads: 64 rows x 64
        int row = q >> 6, co = (q & 63) * 4;
        float4 v = make_float4(zf[row][co], zf[row][co + 1], zf[row][co + 2], zf[row][co + 3]);
        *(float4*)(z32t + (size_t)(r0 + row) * 256 + co) = v;
    }
}

// ---------------------------------------------------------------- helpers
__device__ __forceinline__ fp16x8 frag_ld(const _Float16* lds, int rc, int ku) {
    int slot = rc * 4 + (ku ^ (rc & 3));
    return *(const fp16x8*)(lds + slot * 8);
}

#define MFMA(d, a, b) d = __builtin_amdgcn_mfma_f32_32x32x16_f16(a, b, d, 0, 0, 0)

__device__ __forceinline__ void ins2(float t, int i, float& t0, int& i0, float& t1, int& i1) {
    if (t < t0 || (t == t0 && i < i0)) { t1 = t0; i1 = i0; t0 = t; i0 = i; }
    else if (t < t1 || (t == t1 && i < i1)) { t1 = t; i1 = i; }
}

// ---------------------------------------------------------------- MFMA top-2, XCD-swizzled
// xcd = id&7 owns ntile strip [xcd*16, xcd*16+16): per-XCD working set = 1 MB z
// + ~512 KB e (slow mtile walk) < 4 MB L2 -> re-reads become XCD-local L2 hits.
__launch_bounds__(256, 4)
__global__ void mfma_top2_kernel(const _Float16* __restrict__ e16, const _Float16* __restrict__ z16,
                                 const float* __restrict__ enorm_g, const float* __restrict__ cnorm_g,
                                 float4* __restrict__ part) {
    __shared__ _Float16 As[2][4096];   // 2 x 8 KB
    __shared__ _Float16 Bs[2][4096];
    __shared__ float enb[128];
    __shared__ float mbuf[128][4];

    const int tid = threadIdx.x;
    const int lane = tid & 63, wid = tid >> 6;
    const int l31 = lane & 31, half = lane >> 5;
    const int wave_m = wid & 1, wave_n = wid >> 1;
    const int id = blockIdx.x;              // 8192
    const int xcd = id & 7, slot = id >> 3;
    const int mtile = slot >> 4;            // 0..63
    const int ntile = (xcd << 4) | (slot & 15);  // 0..127

    const float4* Ap = (const float4*)(e16 + (size_t)mtile * 8 * 512 * 8);
    const float4* Bp = (const float4*)(z16 + (size_t)ntile * 8 * 512 * 8);

    if (tid < 128) enb[tid] = enorm_g[mtile * 128 + tid];
    float Cn[2];
    Cn[0] = cnorm_g[ntile * 128 + wave_n * 64 + l31];
    Cn[1] = cnorm_g[ntile * 128 + wave_n * 64 + 32 + l31];

    const int rcA0 = wave_m * 64 + l31, rcA1 = rcA0 + 32;
    const int rcB0 = wave_n * 64 + l31, rcB1 = rcB0 + 32;

    // prologue: kb=0 into buffer 0
    {
        float4 ra0 = Ap[tid], ra1 = Ap[256 + tid];
        float4 rb0 = Bp[tid], rb1 = Bp[256 + tid];
        ((float4*)As[0])[tid] = ra0; ((float4*)As[0])[256 + tid] = ra1;
        ((float4*)Bs[0])[tid] = rb0; ((float4*)Bs[0])[256 + tid] = rb1;
    }
    __syncthreads();

    floatx16 acc00 = (floatx16)0.f, acc01 = (floatx16)0.f,
             acc10 = (floatx16)0.f, acc11 = (floatx16)0.f;

    for (int kb = 0; kb < 8; kb++) {
        const int cur = kb & 1;
        float4 ra0, ra1, rb0, rb1;
        if (kb < 7) {   // register prefetch of next tile
            const int nb = (kb + 1) * 512;
            ra0 = Ap[nb + tid]; ra1 = Ap[nb + 256 + tid];
            rb0 = Bp[nb + tid]; rb1 = Bp[nb + 256 + tid];
        }
#pragma unroll
        for (int ks = 0; ks < 2; ks++) {
            const int ku = ks * 2 + half;
            fp16x8 a0 = frag_ld(As[cur], rcA0, ku);
            fp16x8 a1 = frag_ld(As[cur], rcA1, ku);
            fp16x8 b0 = frag_ld(Bs[cur], rcB0, ku);
            fp16x8 b1 = frag_ld(Bs[cur], rcB1, ku);
            MFMA(acc00, a0, b0);
            MFMA(acc01, a0, b1);
            MFMA(acc10, a1, b0);
            MFMA(acc11, a1, b1);
        }
        if (kb < 7) {
            ((float4*)As[cur ^ 1])[tid] = ra0; ((float4*)As[cur ^ 1])[256 + tid] = ra1;
            ((float4*)Bs[cur ^ 1])[tid] = rb0; ((float4*)Bs[cur ^ 1])[256 + tid] = rb1;
        }
        __syncthreads();
    }

    // fold: C/D 32x32: col = lane&31 (zrow), row = (reg&3)+8*(reg>>2)+4*half (code)
    float t0s[2] = {FLT_MAX, FLT_MAX}, t1s[2] = {FLT_MAX, FLT_MAX};
    int   i0s[2] = {0x7fffffff, 0x7fffffff}, i1s[2] = {0x7fffffff, 0x7fffffff};
#pragma unroll
    for (int mt = 0; mt < 2; mt++) {
#pragma unroll
        for (int reg = 0; reg < 16; reg++) {
            const int rl = (reg & 3) + 8 * (reg >> 2) + 4 * half;
            const int cloc = wave_m * 64 + mt * 32 + rl;
            const int code = mtile * 128 + cloc;
            const float E = enb[cloc];
            float g0 = (mt == 0) ? acc00[reg] : acc10[reg];
            float g1 = (mt == 0) ? acc01[reg] : acc11[reg];
            ins2(fmaf(-0.0078125f, g0, Cn[0] + E), code, t0s[0], i0s[0], t1s[0], i1s[0]);
            ins2(fmaf(-0.0078125f, g1, Cn[1] + E), code, t0s[1], i0s[1], t1s[1], i1s[1]);
        }
    }
#pragma unroll
    for (int s = 0; s < 2; s++) {
        float o0 = __shfl_xor(t0s[s], 32), o1 = __shfl_xor(t1s[s], 32);
        int  oi0 = __shfl_xor(i0s[s], 32), oi1 = __shfl_xor(i1s[s], 32);
        ins2(o0, oi0, t0s[s], i0s[s], t1s[s], i1s[s]);
        ins2(o1, oi1, t0s[s], i0s[s], t1s[s], i1s[s]);
    }
    __syncthreads();
    if (wave_m == 1 && lane < 32) {
#pragma unroll
        for (int s = 0; s < 2; s++) {
            int zr = wave_n * 64 + s * 32 + l31;
            mbuf[zr][0] = t0s[s]; mbuf[zr][1] = t1s[s];
            mbuf[zr][2] = __int_as_float(i0s[s]); mbuf[zr][3] = __int_as_float(i1s[s]);
        }
    }
    __syncthreads();
    if (wave_m == 0 && lane < 32) {
#pragma unroll
        for (int s = 0; s < 2; s++) {
            int zr = wave_n * 64 + s * 32 + l31;
            ins2(mbuf[zr][0], __float_as_int(mbuf[zr][2]), t0s[s], i0s[s], t1s[s], i1s[s]);
            ins2(mbuf[zr][1], __float_as_int(mbuf[zr][3]), t0s[s], i0s[s], t1s[s], i1s[s]);
            float4 o;
            o.x = t0s[s]; o.y = t1s[s];
            o.z = __int_as_float(i0s[s]); o.w = __int_as_float(i1s[s]);
            part[(size_t)(ntile * 128 + zr) * 64 + mtile] = o;
        }
    }
}

// ---------------------------------------------------------------- fp64 rescore, lane-parallel
// lane g owns part entry g (coalesced); min2 by butterfly; ballot shortlist.
__global__ void rescore_kernel(const float* __restrict__ z32t, const float* __restrict__ emb,
                               const float* __restrict__ enorm_g, const float* __restrict__ cnorm_g,
                               const float4* __restrict__ part, float* __restrict__ out,
                               int* __restrict__ ws_i0, int* __restrict__ hist,
                               double* __restrict__ t0sum) {
    const int tid  = threadIdx.x;
    const int lane = tid & 63, wid = tid >> 6;
    const int r = blockIdx.x * 4 + wid;       // 4096 blocks x 4 waves

    float4 p = part[(size_t)r * 64 + lane];
    const float tv0 = p.x, tv1 = p.y;
    const int jv0 = __float_as_int(p.z), jv1 = __float_as_int(p.w);

    // wave-wide two smallest of the 128 candidate scores
    float a = fminf(tv0, tv1), bmx = fmaxf(tv0, tv1);
#pragma unroll
    for (int m = 1; m < 64; m <<= 1) {
        float oa = __shfl_xor(a, m), ob = __shfl_xor(bmx, m);
        float na = fminf(a, oa);
        bmx = fminf(fmaxf(a, oa), fminf(bmx, ob));
        a = na;
    }
    const float T = bmx + 1.2e-4f;   // R5-validated slack
    const float C = cnorm_g[r];

    const int c4 = lane * 4;
    float4 zv = *(const float4*)(z32t + (size_t)r * 256 + c4);
    const double zv0 = (double)zv.x, zv1 = (double)zv.y, zv2 = (double)zv.z, zv3 = (double)zv.w;

    float bt0 = FLT_MAX, bt1 = FLT_MAX;
    int   bi0 = NE - 1, bi1 = NE - 1;
    unsigned long long msk[2];
    msk[0] = __ballot(tv0 <= T);
    msk[1] = __ballot(tv1 <= T);
    for (int pass = 0; pass < 2; pass++) {
        unsigned long long mm = msk[pass];
        while (mm) {
            int g = __builtin_ctzll(mm);
            mm &= mm - 1;
            int j = __shfl(pass ? jv1 : jv0, g) & (NE - 1);
            float4 ev = *(const float4*)(emb + ((size_t)j << 8) + c4);
            double gl = zv0 * (double)ev.x + zv1 * (double)ev.y +
                        zv2 * (double)ev.z + zv3 * (double)ev.w;
#pragma unroll
            for (int m = 1; m < 64; m <<= 1) gl += __shfl_xor(gl, m);
            float g2 = (float)(2.0 * gl);
            float tex = (C + enorm_g[j]) - g2;
            if (tex < bt0 || (tex == bt0 && j < bi0)) {
                bt1 = bt0; bi1 = bi0; bt0 = tex; bi0 = j;
            } else if (tex < bt1 || (tex == bt1 && j < bi1)) {
                bt1 = tex; bi1 = j;
            }
        }
    }

    if (lane == 0) {
        out[OFF_I0 + r] = (float)bi0;
        out[OFF_I1 + r] = (float)bi1;
        ws_i0[r] = bi0;
        atomicAdd(&hist[bi0], 1);
    }
    __shared__ double red[4];
    if (lane == 0) red[wid] = (double)bt0;
    __syncthreads();
    if (tid == 0) atomicAdd(t0sum, (red[0] + red[1]) + (red[2] + red[3]));
}

// ---------------------------------------------------------------- z_q gather (LDS transpose)
__global__ void zq_kernel(const float* __restrict__ emb, const int* __restrict__ ws_i0,
                          float* __restrict__ out) {
    __shared__ float zt[64][65];
    const int tid = threadIdx.x;          // 256
    const int r0  = blockIdx.x * 64;      // 256 blocks
    const int b   = r0 >> 10;
    const int hw0 = r0 & 1023;
    const int kb  = blockIdx.y;           // 4 chunks of 64 channels
#pragma unroll
    for (int p = 0; p < 4; p++) {
        int q = p * 256 + tid;            // 1024 quads: 64 rows x 16
        int row = q >> 4, co = (q & 15) * 4;
        int idx = ws_i0[r0 + row] & (NE - 1);
        float4 v = *(const float4*)(emb + ((size_t)idx << 8) + kb * 64 + co);
        zt[row][co + 0] = v.x; zt[row][co + 1] = v.y;
        zt[row][co + 2] = v.z; zt[row][co + 3] = v.w;
    }
    __syncthreads();
#pragma unroll
    for (int p = 0; p < 4; p++) {
        int q = p * 256 + tid;            // 1024: 64 c x 16 hw-quads
        int c = q >> 4, h4 = (q & 15) * 4;
        float4 v = make_float4(zt[h4 + 0][c], zt[h4 + 1][c], zt[h4 + 2][c], zt[h4 + 3][c]);
        *(float4*)(out + OFF_ZQ + (((size_t)b * 256 + kb * 64 + c) << 10) + hw0 + h4) = v;
    }
}

// ---------------------------------------------------------------- finalize
__global__ void finalize_kernel(const int* __restrict__ hist, const double* __restrict__ t0sum,
                                float* __restrict__ out) {
    __shared__ float red[256];
    float s = 0.f;
    for (int j = threadIdx.x; j < NE; j += 256) {
        float p = (float)hist[j] * (1.0f / 16384.0f);
        s += p * logf(p + 1e-10f);
    }
    red[threadIdx.x] = s;
    __syncthreads();
    for (int m = 128; m; m >>= 1) {
        if (threadIdx.x < m) red[threadIdx.x] += red[threadIdx.x + m];
        __syncthreads();
    }
    if (threadIdx.x == 0) {
        out[OFF_PERP] = expf(-red[0]);
        out[OFF_LOSS] = 1.25f * (float)(t0sum[0] * (1.0 / 4194304.0));
    }
}

extern "C" void kernel_launch(void* const* d_in, const int* in_sizes, int n_in,
                              void* d_out, int out_size, void* d_ws, size_t ws_size,
                              hipStream_t stream) {
    const float* z   = (const float*)d_in[0];
    const float* emb = (const float*)d_in[1];
    float* out = (float*)d_out;
    float* ws  = (float*)d_ws;

    int*    ws_i0    = (int*)ws + WS_I0;
    int*    ws_hist  = (int*)ws + WS_HIST;
    float*  ws_enorm = ws + WS_ENORM;
    float*  ws_cnorm = ws + WS_CNORM;
    double* ws_t0sum = (double*)(ws + WS_T0SUM);

    float* scr = out + OFF_ONEHOT + 2;   // 16B-aligned scratch in one-hot region
    _Float16* z16 = (_Float16*)(scr + SCR_Z16);
    _Float16* e16 = (_Float16*)(scr + SCR_E16);
    float*  z32t  = scr + SCR_Z32T;
    float4* part  = (float4*)(scr + SCR_PART);

    hipLaunchKernelGGL(split_e_kernel, dim3(512), dim3(256), 0, stream,
                       emb, e16, ws_enorm, ws_hist, ws);
    hipLaunchKernelGGL(split_z_kernel, dim3(256), dim3(256), 0, stream,
                       z, z16, z32t, ws_cnorm);
    hipLaunchKernelGGL(mfma_top2_kernel, dim3(8192), dim3(256), 0, stream,
                       e16, z16, ws_enorm, ws_cnorm, part);
    hipLaunchKernelGGL(rescore_kernel, dim3(4096), dim3(256), 0, stream,
                       z32t, emb, ws_enorm, ws_cnorm, part, out, ws_i0, ws_hist, ws_t0sum);
    hipLaunchKernelGGL(zero_onehot_kernel, dim3(4096), dim3(1024), 0, stream, out);
    hipLaunchKernelGGL(scatter_ones_kernel, dim3(64), dim3(256), 0, stream, ws_i0, out);
    hipLaunchKernelGGL(zq_kernel, dim3(256, 4), dim3(256), 0, stream, emb, ws_i0, out);
    hipLaunchKernelGGL(finalize_kernel, dim3(1), dim3(256), 0, stream,
                       ws_hist, ws_t0sum, out);
}